// Round 3
// baseline (111343.787 us; speedup 1.0000x reference)
//
#include <hip/hip_runtime.h>
#include <math.h>

// B=256 T=512 DIN=25 P=128 HID=256 3H=768 L=5 Q=0.15 EPS=1e-5
// Full-fp32 pipeline. Batch processed in sequential groups of Bg samples so
// the fp32 working set fits ws_size (fp16 fallback removed — it broke top-k
// selection and failed absmax). Time axis chunked in 8x64; per chunk one GEMM
// computes input gates for fwd chunk c / bwd chunk 7-c, then the recurrence
// advances both directions 64 steps with h state persisted in global.

#define CH_ 64
#define NCH_ 8

// ---------------- weight transposes (once per call) ----------------
__global__ __launch_bounds__(256)
void prep_wihT_k(const float* __restrict__ Wih0, const float* __restrict__ Wih,
                 float* __restrict__ out)
{
    int id = blockIdx.x * 256 + threadIdx.x;   // exactly 3,342,336 threads
    if (id < 196608) {
        int k = id / 1536, n = id % 1536;
        int d = n / 768, g = n % 768;
        out[id] = Wih0[(size_t)(d * 768 + g) * 128 + k];
    } else {
        int r = id - 196608;
        int l = r / 786432, rr = r % 786432;   // l = layer-1 (0..3)
        int k = rr / 1536, n = rr % 1536;
        int d = n / 768, g = n % 768;
        out[id] = Wih[(size_t)((l * 2 + d) * 768 + g) * 512 + k];
    }
}

__global__ __launch_bounds__(256)
void prep_whhT_k(const float* __restrict__ Whh0, const float* __restrict__ Whh,
                 float* __restrict__ out)
{
    int id = blockIdx.x * 256 + threadIdx.x;   // exactly 1,966,080 threads
    int u = id / 196608, rr = id % 196608;     // u = l*2+d
    int k = rr / 768, c = rr % 768;
    int l = u >> 1, d = u & 1;
    out[id] = (l == 0) ? Whh0[(size_t)(d * 768 + c) * 256 + k]
                       : Whh[(size_t)(((l - 1) * 2 + d) * 768 + c) * 256 + k];
}

// ---------------- input projection: LN -> FC(25->128) -> GELU -> FC(128->128) --
__global__ __launch_bounds__(128)
void input_proj_k(const float* __restrict__ x, const int* __restrict__ lengths,
                  const float* __restrict__ lng, const float* __restrict__ lnb,
                  const float* __restrict__ w1, const float* __restrict__ b1v,
                  const float* __restrict__ w2, const float* __restrict__ b2v,
                  float* __restrict__ out, int b_base)
{
    const int btl = blockIdx.x;                // group-local (b_local*512 + t)
    const int bl  = btl >> 9;
    const int t   = btl & 511;
    const int b   = b_base + bl;
    if (t >= lengths[b]) return;               // masked rows never read downstream
    const int tid = threadIdx.x;
    __shared__ float xs[25];
    __shared__ float xn[25];
    __shared__ float hs[128];
    if (tid < 25) xs[tid] = x[((size_t)b * 512 + t) * 25 + tid];
    __syncthreads();
    if (tid < 25) {
        float mu = 0.f;
        #pragma unroll
        for (int k = 0; k < 25; k++) mu += xs[k];
        mu *= (1.f / 25.f);
        float var = 0.f;
        #pragma unroll
        for (int k = 0; k < 25; k++) { float dd = xs[k] - mu; var += dd * dd; }
        var *= (1.f / 25.f);
        float rstd = 1.f / sqrtf(var + 1e-5f);
        xn[tid] = (xs[tid] - mu) * rstd * lng[tid] + lnb[tid];
    }
    __syncthreads();
    float a = b1v[tid];
    #pragma unroll
    for (int k = 0; k < 25; k++) a = fmaf(xn[k], w1[k * 128 + tid], a);
    float ge = 0.5f * a * (1.f + erff(a * 0.70710678118654752440f));
    hs[tid] = ge;
    __syncthreads();
    float o = b2v[tid];
    #pragma unroll 8
    for (int k = 0; k < 128; k++) o = fmaf(hs[k], w2[k * 128 + tid], o);
    out[(size_t)btl * 128 + tid] = o;
}

// ---------------- per-chunk input-gate GEMM ----------------
// grid (6, Bg): nt = col tile (128 cols of 768); y<Bg/2 -> dir0 rows of fwd
// chunk lo_f, else dir1 rows of bwd chunk lo_b. Two samples per 128-row tile.
__global__ __launch_bounds__(256, 2)
void gemm_chunk_k(const float* __restrict__ A, int K,
                  const float* __restrict__ Bt, const float* __restrict__ bias,
                  const int* __restrict__ lengths, int lo_f, int lo_b,
                  float* __restrict__ C, int b_base, int halfY, int dirStride)
{
    const int nt  = blockIdx.x;                // 0..5
    const int my  = blockIdx.y;
    const int dir = (my >= halfY) ? 1 : 0;
    const int mtl = my - dir * halfY;          // 0..halfY-1
    const int lo  = dir ? lo_b : lo_f;
    const int bs0 = mtl * 2;                   // group-local sample pair
    if (lengths[b_base + bs0] <= lo && lengths[b_base + bs0 + 1] <= lo) return;
    const int n0  = nt << 7;
    const int cb  = dir * 768 + n0;            // column base in Bt/bias
    const int tid = threadIdx.x;

    __shared__ float As[8][128];               // [k][m]
    __shared__ float Bs[8][132];               // [k][n] (+pad)

    float acc[8][8] = {};

    const int tx8 = (tid & 15) << 3;
    const int ty8 = (tid >> 4) << 3;
    const int am  = tid >> 1;
    const int ah  = (tid & 1) << 2;
    const int bk  = tid >> 5;
    const int bn  = (tid & 31) << 2;

    const int ra = mtl * 128 + am;             // local row in chunk matrix
    const float* Ap = A + (size_t)((ra >> 6) * 512 + lo + (ra & 63)) * K + ah;
    const float* Bp = Bt + (size_t)bk * 1536 + cb + bn;

    for (int k0 = 0; k0 < K; k0 += 8) {
        float4 av = *(const float4*)(Ap + k0);
        float4 bv = *(const float4*)(Bp + (size_t)k0 * 1536);
        __syncthreads();
        As[ah + 0][am] = av.x;
        As[ah + 1][am] = av.y;
        As[ah + 2][am] = av.z;
        As[ah + 3][am] = av.w;
        *(float4*)(&Bs[bk][bn]) = bv;
        __syncthreads();
        #pragma unroll
        for (int kk = 0; kk < 8; kk++) {
            float4 x0 = *(const float4*)(&As[kk][ty8]);
            float4 x1 = *(const float4*)(&As[kk][ty8 + 4]);
            float4 y0 = *(const float4*)(&Bs[kk][tx8]);
            float4 y1 = *(const float4*)(&Bs[kk][tx8 + 4]);
            float ar[8] = {x0.x, x0.y, x0.z, x0.w, x1.x, x1.y, x1.z, x1.w};
            float br[8] = {y0.x, y0.y, y0.z, y0.w, y1.x, y1.y, y1.z, y1.w};
            #pragma unroll
            for (int i = 0; i < 8; i++)
                #pragma unroll
                for (int j = 0; j < 8; j++)
                    acc[i][j] = fmaf(ar[i], br[j], acc[i][j]);
        }
    }

    float bsv[8];
    #pragma unroll
    for (int j = 0; j < 8; j++) bsv[j] = bias[cb + tx8 + j];
    #pragma unroll
    for (int i = 0; i < 8; i++) {
        int r = mtl * 128 + ty8 + i;           // == local_sample*64 + (p-lo)
        float* crow = C + (size_t)dir * dirStride + (size_t)r * 768 + n0 + tx8;
        float4 c0 = make_float4(acc[i][0] + bsv[0], acc[i][1] + bsv[1],
                                acc[i][2] + bsv[2], acc[i][3] + bsv[3]);
        float4 c1 = make_float4(acc[i][4] + bsv[4], acc[i][5] + bsv[5],
                                acc[i][6] + bsv[6], acc[i][7] + bsv[7]);
        *(float4*)(crow)     = c0;
        *(float4*)(crow + 4) = c1;
    }
}

// ---------------- chunked masked bidirectional GRU recurrence ----------------
// grid = 2*(Bg/4) blocks x 768 thr: d = blk/nTiles, tile = blk%nTiles (4 samp).
// fwd ascends positions in [lo,lo+64), bwd descends; sample updates only when
// p < len (== step-indexed reference semantics). h state persisted in hstate.
__global__ __launch_bounds__(768)
void recur_chunk_k(const float* __restrict__ xwc, const float* __restrict__ Wt2,
                   const float* __restrict__ bhh2, const int* __restrict__ lengths,
                   float* __restrict__ Y, float* __restrict__ hstate,
                   int lo_f, int lo_b, int first, int b_base, int nTiles,
                   int dirStride)
{
    const int d    = blockIdx.x / nTiles;
    const int tile = blockIdx.x - d * nTiles;
    const int b0l  = tile * 4;                 // group-local
    const int tid  = threadIdx.x;
    const int lo   = d ? lo_b : lo_f;
    const int hi   = lo + CH_;

    const int l0 = lengths[b_base + b0l],     l1 = lengths[b_base + b0l + 1];
    const int l2 = lengths[b_base + b0l + 2], l3 = lengths[b_base + b0l + 3];
    const int maxlen = max(max(l0, l1), max(l2, l3));
    if (!first && maxlen <= lo) return;        // state already valid

    __shared__ float h_s[256][4];              // [k][b]: one float4 per k
    __shared__ float gh_s[4][776];             // +8 pad vs bank conflicts
    __shared__ float bhh_s[768];
    __shared__ int   len_s[4];

    bhh_s[tid] = bhh2[d * 768 + tid];
    if (tid < 4) len_s[tid] = lengths[b_base + b0l + tid];
    float* hg = hstate + (size_t)(d * nTiles + tile) * 1024;
    for (int i = tid; i < 1024; i += 768)
        ((float*)h_s)[i] = first ? 0.f : hg[i];
    __syncthreads();

    const float* Wt  = Wt2 + (size_t)d * 196608;     // [256][768]
    const float* xwd = xwc + (size_t)d * dirStride;
    const int c = tid;                               // gate column 0..767

    const int nit = min(hi, maxlen) - lo;            // may be <=0 on first
    for (int s = 0; s < nit; s++) {
        const int p = d ? (min(hi, maxlen) - 1 - s) : (lo + s);
        float a0 = bhh_s[c], a1 = a0, a2 = a0, a3 = a0;
        const float* wp = Wt + c;
        #pragma unroll 8
        for (int k = 0; k < 256; k++) {
            float wv = wp[(size_t)k * 768];          // coalesced across lanes
            float4 h4 = *(const float4*)(&h_s[k][0]);// uniform addr -> broadcast
            a0 = fmaf(h4.x, wv, a0);
            a1 = fmaf(h4.y, wv, a1);
            a2 = fmaf(h4.z, wv, a2);
            a3 = fmaf(h4.w, wv, a3);
        }
        gh_s[0][c] = a0; gh_s[1][c] = a1; gh_s[2][c] = a2; gh_s[3][c] = a3;
        __syncthreads();
        #pragma unroll
        for (int it = 0; it < 2; it++) {
            int idx = tid + it * 768;
            if (idx < 1024) {
                int bb = idx >> 8;
                int j  = idx & 255;
                if (p < len_s[bb]) {
                    int bl = b0l + bb;               // group-local sample
                    const float* xr = xwd + (size_t)(bl * 64 + (p - lo)) * 768;
                    float gr = gh_s[bb][j];
                    float gz = gh_s[bb][256 + j];
                    float gn = gh_s[bb][512 + j];
                    float r = 1.f / (1.f + expf(-(xr[j] + gr)));
                    float z = 1.f / (1.f + expf(-(xr[256 + j] + gz)));
                    float n = tanhf(xr[512 + j] + r * gn);
                    float hv = h_s[j][bb];
                    float hn = (1.f - z) * n + z * hv;
                    h_s[j][bb] = hn;
                    Y[((size_t)bl * 512 + p) * 512 + d * 256 + j] = hn;
                }
            }
        }
        __syncthreads();
    }
    for (int i = tid; i < 1024; i += 768) hg[i] = ((float*)h_s)[i];
}

// ---------------- top-Q pooling + classifier head ----------------
__global__ __launch_bounds__(256)
void pool_k(const float* __restrict__ H, const int* __restrict__ lengths,
            const float* __restrict__ Wc, const float* __restrict__ bcp,
            float* __restrict__ out, int b_base)
{
    const int bl = blockIdx.x;                 // group-local
    const int b  = b_base + bl;
    const int tid = threadIdx.x;
    __shared__ float sc[512];
    __shared__ int   sel[128];
    __shared__ int   nsel;
    __shared__ float red[256];
    const int len = lengths[b];
    const int k = max(1, (int)ceilf((float)len * 0.15f));   // jnp fp32 semantics
    if (tid == 0) nsel = 0;
    for (int t = tid; t < 512; t += 256) {
        float s;
        if (t < len) {
            const float* row = H + ((size_t)bl * 512 + t) * 512;
            float acc = 0.f;
            for (int j = 0; j < 512; j++) acc = fmaf(row[j], row[j], acc);
            s = sqrtf(acc);
        } else s = -1e9f;                      // never read poison rows
        sc[t] = s;
    }
    __syncthreads();
    // stable top-k: include t iff (#strictly greater) + (#equal, smaller idx) < k
    for (int t = tid; t < 512; t += 256) {
        if (t < len) {
            const float s = sc[t];
            int cnt = 0;
            for (int u = 0; u < 512; u++) {
                float su = sc[u];
                cnt += (su > s || (su == s && u < t)) ? 1 : 0;
            }
            if (cnt < k) { int p = atomicAdd(&nsel, 1); sel[p] = t; }
        }
    }
    __syncthreads();
    const int ns = nsel;                       // == k
    float part = 0.f;
    for (int j = tid; j < 512; j += 256) {
        float acc = 0.f;
        for (int i = 0; i < ns; i++)
            acc += H[((size_t)bl * 512 + sel[i]) * 512 + j];
        part += (acc / (float)k) * Wc[j];
    }
    red[tid] = part;
    __syncthreads();
    for (int s2 = 128; s2 > 0; s2 >>= 1) {
        if (tid < s2) red[tid] += red[tid + s2];
        __syncthreads();
    }
    if (tid == 0) out[b] = red[0] + bcp[0];
}

// ---------------- host ----------------
static inline size_t alup(size_t x) { return (x + 255) & ~255ull; }

static size_t tier_bytes(int Bg)
{
    return 2 * alup((size_t)Bg * 512 * 512 * 4)        // ping-pong H buffers
         + alup((size_t)Bg * 2 * 64 * 768 * 4)         // xw chunk (both dirs)
         + alup(3342336ull * 4)                        // wihT
         + alup(1966080ull * 4)                        // whhT
         + alup((size_t)Bg * 2048);                    // hstate
}

extern "C" void kernel_launch(void* const* d_in, const int* in_sizes, int n_in,
                              void* d_out, int out_size, void* d_ws, size_t ws_size,
                              hipStream_t stream)
{
    const float* x    = (const float*)d_in[0];
    const int*   len  = (const int*)  d_in[1];
    const float* ln_g = (const float*)d_in[2];
    const float* ln_b = (const float*)d_in[3];
    const float* w1   = (const float*)d_in[4];
    const float* b1   = (const float*)d_in[5];
    const float* w2   = (const float*)d_in[6];
    const float* b2   = (const float*)d_in[7];
    const float* Wih0 = (const float*)d_in[8];
    const float* Whh0 = (const float*)d_in[9];
    const float* bih0 = (const float*)d_in[10];
    const float* bhh0 = (const float*)d_in[11];
    const float* Wih  = (const float*)d_in[12];
    const float* Whh  = (const float*)d_in[13];
    const float* bih  = (const float*)d_in[14];
    const float* bhh  = (const float*)d_in[15];
    const float* Wc   = (const float*)d_in[16];
    const float* bc   = (const float*)d_in[17];
    float* out = (float*)d_out;

    int Bg = 0;
    const int tiers[6] = {256, 128, 64, 32, 16, 8};
    for (int i = 0; i < 6; i++)
        if (ws_size >= tier_bytes(tiers[i])) { Bg = tiers[i]; break; }
    if (Bg == 0) return;   // clean fail: ws too small for any fp32 tier

    char* ws = (char*)d_ws;
    size_t off = 0;
    auto alloc = [&](size_t bytes) { size_t o = off; off += alup(bytes); return o; };
    float* h0   = (float*)(ws + alloc((size_t)Bg * 512 * 512 * 4));
    float* h1   = (float*)(ws + alloc((size_t)Bg * 512 * 512 * 4));
    float* xwc  = (float*)(ws + alloc((size_t)Bg * 2 * 64 * 768 * 4));
    float* wihT = (float*)(ws + alloc(3342336ull * 4));
    float* whhT = (float*)(ws + alloc(1966080ull * 4));
    float* hst  = (float*)(ws + alloc((size_t)Bg * 2048));

    prep_wihT_k<<<13056, 256, 0, stream>>>(Wih0, Wih, wihT);
    prep_whhT_k<<<7680, 256, 0, stream>>>(Whh0, Whh, whhT);

    const int halfY     = Bg / 2;
    const int nTiles    = Bg / 4;
    const int dirStride = Bg * 64 * 768;       // floats per direction in xwc

    for (int b_base = 0; b_base < 256; b_base += Bg) {
        input_proj_k<<<Bg * 512, 128, 0, stream>>>(x, len, ln_g, ln_b, w1, b1,
                                                   w2, b2, h0, b_base);
        float* bin = h0;
        float* bout = h1;
        for (int l = 0; l < 5; l++) {
            const int K = (l == 0) ? 128 : 512;
            const float* wt = wihT + ((l == 0) ? 0 : (196608 + (size_t)(l - 1) * 786432));
            const float* bi = (l == 0) ? bih0 : (bih + (size_t)(l - 1) * 1536);
            const float* wh = whhT + (size_t)l * 2 * 196608;
            const float* bh = (l == 0) ? bhh0 : (bhh + (size_t)(l - 1) * 1536);
            for (int c = 0; c < NCH_; c++) {
                const int lo_f = c * CH_;
                const int lo_b = (NCH_ - 1 - c) * CH_;
                gemm_chunk_k<<<dim3(6, Bg), 256, 0, stream>>>(
                    bin, K, wt, bi, len, lo_f, lo_b, xwc, b_base, halfY, dirStride);
                recur_chunk_k<<<2 * nTiles, 768, 0, stream>>>(
                    xwc, wh, bh, len, bout, hst, lo_f, lo_b, c == 0, b_base,
                    nTiles, dirStride);
            }
            float* tmp = bin; bin = bout; bout = tmp;
        }
        pool_k<<<Bg, 256, 0, stream>>>(bin, len, Wc, bc, out, b_base);
    }
}

// Round 4
// 70939.069 us; speedup vs baseline: 1.5696x; 1.5696x over previous
//
#include <hip/hip_runtime.h>
#include <math.h>

// B=256 T=512 DIN=25 P=128 HID=256 3H=768 L=5 Q=0.15 EPS=1e-5
// Full-fp32. Batch in groups of Bg (ws-tiered). Time axis in 8 chunks of 64.
// Per (group,layer): 9 fused rounds r=0..8: gemm-role blocks compute input
// gates for fwd chunk r / bwd chunk 7-r into xwbuf[r&1]; recur-role blocks
// (one block per sample-dir, 256 thr) advance chunk r-1 from xwbuf[(r-1)&1].
// GEMM overlaps recurrence on otherwise-idle CUs.

#define CH 64

// ---------------- Whh transpose: whhT[l][d][k][c] ----------------
__global__ __launch_bounds__(256)
void prep_whhT_k(const float* __restrict__ Whh0, const float* __restrict__ Whh,
                 float* __restrict__ out)
{
    int id = blockIdx.x * 256 + threadIdx.x;   // exactly 1,966,080 threads
    int u = id / 196608, rr = id % 196608;     // u = l*2+d
    int k = rr / 768, c = rr % 768;
    int l = u >> 1, d = u & 1;
    out[id] = (l == 0) ? Whh0[(size_t)(d * 768 + c) * 256 + k]
                       : Whh[(size_t)(((l - 1) * 2 + d) * 768 + c) * 256 + k];
}

// ---------------- input projection: LN -> FC(25->128) -> GELU -> FC(128->128) --
__global__ __launch_bounds__(128)
void input_proj_k(const float* __restrict__ x, const int* __restrict__ lengths,
                  const float* __restrict__ lng, const float* __restrict__ lnb,
                  const float* __restrict__ w1, const float* __restrict__ b1v,
                  const float* __restrict__ w2, const float* __restrict__ b2v,
                  float* __restrict__ out, int b_base)
{
    const int btl = blockIdx.x;                // group-local (bl*512 + t)
    const int bl  = btl >> 9;
    const int t   = btl & 511;
    const int b   = b_base + bl;
    if (t >= lengths[b]) return;               // masked rows never read downstream
    const int tid = threadIdx.x;
    __shared__ float xs[25];
    __shared__ float xn[25];
    __shared__ float hs[128];
    if (tid < 25) xs[tid] = x[((size_t)b * 512 + t) * 25 + tid];
    __syncthreads();
    if (tid < 25) {
        float mu = 0.f;
        #pragma unroll
        for (int k = 0; k < 25; k++) mu += xs[k];
        mu *= (1.f / 25.f);
        float var = 0.f;
        #pragma unroll
        for (int k = 0; k < 25; k++) { float dd = xs[k] - mu; var += dd * dd; }
        var *= (1.f / 25.f);
        float rstd = 1.f / sqrtf(var + 1e-5f);
        xn[tid] = (xs[tid] - mu) * rstd * lng[tid] + lnb[tid];
    }
    __syncthreads();
    float a = b1v[tid];
    #pragma unroll
    for (int k = 0; k < 25; k++) a = fmaf(xn[k], w1[k * 128 + tid], a);
    float ge = 0.5f * a * (1.f + erff(a * 0.70710678118654752440f));
    hs[tid] = ge;
    __syncthreads();
    float o = b2v[tid];
    #pragma unroll 8
    for (int k = 0; k < 128; k++) o = fmaf(hs[k], w2[k * 128 + tid], o);
    out[(size_t)btl * 128 + tid] = o;
}

// ---------------- fused round: gemm(chunk r) + recur(chunk r-1) ----------------
// blocks [0, NG): GEMM role. 64Mx128N tile, A = H_l rows (stride K), B = raw
//   Wih slice [2][768][K] transposed in LDS. Out: xw_w[(d*Bg+s)*64 + row][768].
// blocks [NG, NG+2*Bg): recur role. One (sample s, dir d) per block, 256 thr.
__global__ __launch_bounds__(256)
void round_k(const float* __restrict__ A, int K,
             const float* __restrict__ W,      // raw Wih layer slice [2][768][K]
             const float* __restrict__ bi,     // [2][768]
             const int* __restrict__ lengths, int b_base, int Bg,
             float* __restrict__ xw_w, int lo_fw, int lo_bw,
             const float* __restrict__ xw_r, int lo_fr, int lo_br,
             const float* __restrict__ whhT,   // layer slice [2][256][768]
             const float* __restrict__ bhh,    // [2][768]
             float* __restrict__ Y,            // bout [Bg*512][512]
             float* __restrict__ hstate,       // [2*Bg][256]
             int NG, int first)
{
    __shared__ float As[8][68];        // gemm: [k][m]
    __shared__ float Bs[8][132];       // gemm: [k][n]
    __shared__ float h_s[260];         // recur: h state
    __shared__ float gs[4][776];       // recur: K-split partial gh

    const int tid = threadIdx.x;

    if ((int)blockIdx.x < NG) {
        // ================= GEMM role =================
        const int gid  = blockIdx.x;
        const int nt   = gid % 6;
        const int rest = gid / 6;
        const int d    = (rest >= Bg) ? 1 : 0;
        const int s    = rest - d * Bg;
        const int lo   = d ? lo_bw : lo_fw;
        if (lengths[b_base + s] <= lo) return;   // chunk fully masked for sample

        float acc[4][8] = {};
        const int tm = tid >> 4;                 // 0..15 -> rows tm*4..+3
        const int tn = tid & 15;                 // cols {tn*4..+3, 64+tn*4..+3}
        const int ar = tid >> 2, ak = (tid & 3) * 2;
        const int bn = tid >> 1, bk = (tid & 1) * 4;

        const float* Ap = A + (size_t)(s * 512 + lo + ar) * K + ak;
        const float* Wp = W + ((size_t)d * 768 + nt * 128 + bn) * K + bk;

        for (int k0 = 0; k0 < K; k0 += 8) {
            float2 av = *(const float2*)(Ap + k0);
            float4 bv = *(const float4*)(Wp + k0);
            __syncthreads();
            As[ak][ar] = av.x; As[ak + 1][ar] = av.y;
            Bs[bk + 0][bn] = bv.x; Bs[bk + 1][bn] = bv.y;
            Bs[bk + 2][bn] = bv.z; Bs[bk + 3][bn] = bv.w;
            __syncthreads();
            #pragma unroll
            for (int kk = 0; kk < 8; kk++) {
                float4 a4 = *(const float4*)&As[kk][tm * 4];
                float4 b0 = *(const float4*)&Bs[kk][tn * 4];
                float4 b1 = *(const float4*)&Bs[kk][64 + tn * 4];
                float ar4[4] = {a4.x, a4.y, a4.z, a4.w};
                float br[8] = {b0.x, b0.y, b0.z, b0.w, b1.x, b1.y, b1.z, b1.w};
                #pragma unroll
                for (int i = 0; i < 4; i++)
                    #pragma unroll
                    for (int j = 0; j < 8; j++)
                        acc[i][j] = fmaf(ar4[i], br[j], acc[i][j]);
            }
        }
        const int cb = d * 768 + nt * 128;
        float bv0[4], bv1[4];
        #pragma unroll
        for (int j = 0; j < 4; j++) {
            bv0[j] = bi[cb + tn * 4 + j];
            bv1[j] = bi[cb + 64 + tn * 4 + j];
        }
        #pragma unroll
        for (int i = 0; i < 4; i++) {
            const int row = tm * 4 + i;
            float* o = xw_w + (size_t)((d * Bg + s) * 64 + row) * 768 + nt * 128 + tn * 4;
            float4 c0 = make_float4(acc[i][0] + bv0[0], acc[i][1] + bv0[1],
                                    acc[i][2] + bv0[2], acc[i][3] + bv0[3]);
            float4 c1 = make_float4(acc[i][4] + bv1[0], acc[i][5] + bv1[1],
                                    acc[i][6] + bv1[2], acc[i][7] + bv1[3]);
            *(float4*)(o)      = c0;
            *(float4*)(o + 64) = c1;
        }
    } else {
        // ================= recur role =================
        const int rid = blockIdx.x - NG;
        const int d   = (rid >= Bg) ? 1 : 0;
        const int s   = rid - d * Bg;
        const int len = lengths[b_base + s];
        const int lo  = d ? lo_br : lo_fr;

        float* hg = hstate + (size_t)(d * Bg + s) * 256;
        h_s[tid] = first ? 0.f : hg[tid];
        __syncthreads();

        const int nst = min(lo + CH, len) - lo;   // active steps (may be <=0)
        const int kq  = tid >> 6;                 // K quarter 0..3
        const int q4  = (tid & 63) * 4;           // col-4 base within gate
        const float* Wd  = whhT + (size_t)d * 196608;
        const float* xwd = xw_r + (size_t)(d * Bg + s) * 64 * 768;
        const float bh0 = bhh[d * 768 + tid];
        const float bh1 = bhh[d * 768 + 256 + tid];
        const float bh2 = bhh[d * 768 + 512 + tid];

        for (int st = 0; st < nst; st++) {
            const int p = d ? (lo + nst - 1 - st) : (lo + st);
            // phase 1: partial gh over this thread's K quarter, 12 cols
            float a0[4] = {}, a1[4] = {}, a2[4] = {};
            const float* wk = Wd + (size_t)(kq * 64) * 768 + q4;
            #pragma unroll 4
            for (int k4 = 0; k4 < 16; k4++) {
                float4 h4 = *(const float4*)&h_s[kq * 64 + k4 * 4];
                const float* w0 = wk + (size_t)(k4 * 4) * 768;
                float hk[4] = {h4.x, h4.y, h4.z, h4.w};
                #pragma unroll
                for (int kk = 0; kk < 4; kk++) {
                    const float* wr = w0 + (size_t)kk * 768;
                    float4 wv0 = *(const float4*)(wr);
                    float4 wv1 = *(const float4*)(wr + 256);
                    float4 wv2 = *(const float4*)(wr + 512);
                    float h = hk[kk];
                    a0[0] = fmaf(h, wv0.x, a0[0]); a0[1] = fmaf(h, wv0.y, a0[1]);
                    a0[2] = fmaf(h, wv0.z, a0[2]); a0[3] = fmaf(h, wv0.w, a0[3]);
                    a1[0] = fmaf(h, wv1.x, a1[0]); a1[1] = fmaf(h, wv1.y, a1[1]);
                    a1[2] = fmaf(h, wv1.z, a1[2]); a1[3] = fmaf(h, wv1.w, a1[3]);
                    a2[0] = fmaf(h, wv2.x, a2[0]); a2[1] = fmaf(h, wv2.y, a2[1]);
                    a2[2] = fmaf(h, wv2.z, a2[2]); a2[3] = fmaf(h, wv2.w, a2[3]);
                }
            }
            *(float4*)&gs[kq][q4]       = make_float4(a0[0], a0[1], a0[2], a0[3]);
            *(float4*)&gs[kq][256 + q4] = make_float4(a1[0], a1[1], a1[2], a1[3]);
            *(float4*)&gs[kq][512 + q4] = make_float4(a2[0], a2[1], a2[2], a2[3]);
            __syncthreads();
            // phase 2: gate update for h-dim j = tid
            float gr = bh0 + gs[0][tid] + gs[1][tid] + gs[2][tid] + gs[3][tid];
            float gz = bh1 + gs[0][256 + tid] + gs[1][256 + tid]
                           + gs[2][256 + tid] + gs[3][256 + tid];
            float gn = bh2 + gs[0][512 + tid] + gs[1][512 + tid]
                           + gs[2][512 + tid] + gs[3][512 + tid];
            const float* xr = xwd + (size_t)(p - lo) * 768;
            float r = 1.f / (1.f + expf(-(xr[tid] + gr)));
            float z = 1.f / (1.f + expf(-(xr[256 + tid] + gz)));
            float n = tanhf(xr[512 + tid] + r * gn);
            float hv = h_s[tid];
            float hn = (1.f - z) * n + z * hv;
            h_s[tid] = hn;
            Y[((size_t)(s * 512 + p)) * 512 + d * 256 + tid] = hn;
            __syncthreads();
        }
        hg[tid] = h_s[tid];
    }
}

// ---------------- top-Q pooling + classifier head ----------------
__global__ __launch_bounds__(256)
void pool_k(const float* __restrict__ H, const int* __restrict__ lengths,
            const float* __restrict__ Wc, const float* __restrict__ bcp,
            float* __restrict__ out, int b_base)
{
    const int bl = blockIdx.x;
    const int b  = b_base + bl;
    const int tid = threadIdx.x;
    __shared__ float sc[512];
    __shared__ int   sel[128];
    __shared__ int   nsel;
    __shared__ float red[256];
    const int len = lengths[b];
    const int k = max(1, (int)ceilf((float)len * 0.15f));   // jnp fp32 semantics
    if (tid == 0) nsel = 0;
    for (int t = tid; t < 512; t += 256) {
        float s;
        if (t < len) {
            const float* row = H + ((size_t)bl * 512 + t) * 512;
            float acc = 0.f;
            for (int j = 0; j < 512; j++) acc = fmaf(row[j], row[j], acc);
            s = sqrtf(acc);
        } else s = -1e9f;
        sc[t] = s;
    }
    __syncthreads();
    // stable top-k: include t iff (#strictly greater) + (#equal, smaller idx) < k
    for (int t = tid; t < 512; t += 256) {
        if (t < len) {
            const float s = sc[t];
            int cnt = 0;
            for (int u = 0; u < 512; u++) {
                float su = sc[u];
                cnt += (su > s || (su == s && u < t)) ? 1 : 0;
            }
            if (cnt < k) { int p = atomicAdd(&nsel, 1); sel[p] = t; }
        }
    }
    __syncthreads();
    const int ns = nsel;                       // == k
    float part = 0.f;
    for (int j = tid; j < 512; j += 256) {
        float acc = 0.f;
        for (int i = 0; i < ns; i++)
            acc += H[((size_t)bl * 512 + sel[i]) * 512 + j];
        part += (acc / (float)k) * Wc[j];
    }
    red[tid] = part;
    __syncthreads();
    for (int s2 = 128; s2 > 0; s2 >>= 1) {
        if (tid < s2) red[tid] += red[tid + s2];
        __syncthreads();
    }
    if (tid == 0) out[b] = red[0] + bcp[0];
}

// ---------------- host ----------------
static inline size_t alup(size_t x) { return (x + 255) & ~255ull; }

static size_t tier_bytes(int Bg)
{
    return 2 * alup((size_t)Bg * 512 * 512 * 4)        // H ping-pong
         + 2 * alup((size_t)Bg * 2 * 64 * 768 * 4)     // xw ping-pong
         + alup(1966080ull * 4)                        // whhT
         + alup((size_t)Bg * 2 * 256 * 4);             // hstate
}

extern "C" void kernel_launch(void* const* d_in, const int* in_sizes, int n_in,
                              void* d_out, int out_size, void* d_ws, size_t ws_size,
                              hipStream_t stream)
{
    const float* x    = (const float*)d_in[0];
    const int*   len  = (const int*)  d_in[1];
    const float* ln_g = (const float*)d_in[2];
    const float* ln_b = (const float*)d_in[3];
    const float* w1   = (const float*)d_in[4];
    const float* b1   = (const float*)d_in[5];
    const float* w2   = (const float*)d_in[6];
    const float* b2   = (const float*)d_in[7];
    const float* Wih0 = (const float*)d_in[8];
    const float* Whh0 = (const float*)d_in[9];
    const float* bih0 = (const float*)d_in[10];
    const float* bhh0 = (const float*)d_in[11];
    const float* Wih  = (const float*)d_in[12];
    const float* Whh  = (const float*)d_in[13];
    const float* bih  = (const float*)d_in[14];
    const float* bhh  = (const float*)d_in[15];
    const float* Wc   = (const float*)d_in[16];
    const float* bc   = (const float*)d_in[17];
    float* out = (float*)d_out;

    int Bg = 0;
    const int tiers[8] = {256, 128, 64, 32, 16, 8, 4, 2};
    for (int i = 0; i < 8; i++)
        if (ws_size >= tier_bytes(tiers[i])) { Bg = tiers[i]; break; }
    if (Bg == 0) return;

    char* ws = (char*)d_ws;
    size_t off = 0;
    auto alloc = [&](size_t bytes) { size_t o = off; off += alup(bytes); return o; };
    float* h0    = (float*)(ws + alloc((size_t)Bg * 512 * 512 * 4));
    float* h1    = (float*)(ws + alloc((size_t)Bg * 512 * 512 * 4));
    float* xwA   = (float*)(ws + alloc((size_t)Bg * 2 * 64 * 768 * 4));
    float* xwB   = (float*)(ws + alloc((size_t)Bg * 2 * 64 * 768 * 4));
    float* whhT  = (float*)(ws + alloc(1966080ull * 4));
    float* hst   = (float*)(ws + alloc((size_t)Bg * 2 * 256 * 4));
    float* xwbuf[2] = {xwA, xwB};

    prep_whhT_k<<<7680, 256, 0, stream>>>(Whh0, Whh, whhT);

    for (int g = 0; g < 256; g += Bg) {
        input_proj_k<<<Bg * 512, 128, 0, stream>>>(x, len, ln_g, ln_b, w1, b1,
                                                   w2, b2, h0, g);
        float* bin = h0;
        float* bout = h1;
        for (int l = 0; l < 5; l++) {
            const int K = (l == 0) ? 128 : 512;
            const float* Wl  = (l == 0) ? Wih0 : (Wih + (size_t)(l - 1) * 2 * 768 * 512);
            const float* bil = (l == 0) ? bih0 : (bih + (size_t)(l - 1) * 1536);
            const float* whl = whhT + (size_t)l * 393216;
            const float* bhl = (l == 0) ? bhh0 : (bhh + (size_t)(l - 1) * 1536);
            for (int r = 0; r <= 8; r++) {
                const int NG = (r < 8) ? 12 * Bg : 0;
                const int NR = (r > 0) ? 2 * Bg : 0;
                round_k<<<NG + NR, 256, 0, stream>>>(
                    bin, K, Wl, bil, len, g, Bg,
                    xwbuf[r & 1], r * 64, (7 - r) * 64,
                    xwbuf[(r & 1) ^ 1], (r - 1) * 64, (8 - r) * 64,
                    whl, bhl, bout, hst, NG, (r == 1) ? 1 : 0);
            }
            float* tmp = bin; bin = bout; bout = tmp;
        }
        pool_k<<<Bg, 256, 0, stream>>>(bin, len, Wc, bc, out, g);
    }
}